// Round 12
// baseline (2665.875 us; speedup 1.0000x reference)
//
#include <hip/hip_runtime.h>

// ---------------------------------------------------------------------------
// BiLSTM-CRF forward loss on MI355X (gfx950).
//
// Round-12: make weight residency REQUIRE NOTHING from the allocator.
//   r6-r11 lesson: at 512 thr the allocator never exceeds 128 VGPR (proven
//   even with 1 block/CU forced via the r11 LDS pad, which DID land:
//   LDS_Block_Size 82432). r9's 1024-thr structure needs only 96 VGPR of
//   weights (124 total) but failed because TWO blocks co-resided -> 8
//   waves/SIMD -> 64-VGPR target.
// This round combines the two proven mechanisms:
//   1024 threads (16 waves, wave owns 4 ntiles, 96-VGPR weights)
//   + volatile-kept LDS pad (82432B -> exactly 1 block/CU -> 4 waves/SIMD,
//     structural 128-VGPR cap that the ~124-VGPR demand fits under)
//   + asm keep-alives on the weight regs (remat deterrent).
// Contract notes (rounds 0-3): output f32; mask int32.
// Workspace layout (bytes):
//   [0)         em: [2][128][512][20] f32            (10485760)
//   [10485760)  whh_f8: [2][64nt][8kt][64lane] i64   (524288)
//   [11010048)  wih_f8: [2][64nt][4kt][64lane] i64   (262144)
//   [11272192)  wout_f8: [2][2nt][8kt][64lane] i64   (16384)
//   [11288576)  bias: [2][1024] f32                  (8192)
//   [11296768)  partial: [128] f32
// ---------------------------------------------------------------------------

typedef float f32x4 __attribute__((ext_vector_type(4)));

#define MFMAF8(a, b, c) \
  __builtin_amdgcn_mfma_f32_16x16x32_fp8_fp8((a), (b), (c), 0, 0, 0)

__device__ __forceinline__ unsigned short f2bf(float x) {
  unsigned u = __float_as_uint(x);
  u += 0x7FFFu + ((u >> 16) & 1u);  // RNE
  return (unsigned short)(u >> 16);
}
__device__ __forceinline__ float bf2f(unsigned short h) {
  return __uint_as_float(((unsigned)h) << 16);
}
__device__ __forceinline__ float sigm(float x) {
  return __builtin_amdgcn_rcpf(1.f + __expf(-x));
}
__device__ __forceinline__ float tanh_(float x) {
  float e = __expf(2.f * x);
  return (e - 1.f) * __builtin_amdgcn_rcpf(e + 1.f);
}
__device__ __forceinline__ unsigned pack_fp8x4(float a, float b, float c, float d) {
  int p = __builtin_amdgcn_cvt_pk_fp8_f32(a, b, 0, false);
  p = __builtin_amdgcn_cvt_pk_fp8_f32(c, d, p, true);
  return (unsigned)p;
}

// ---------------------------------------------------------------------------
// K0: weight prep: f32 -> fp8 e4m3 MFMA B-fragments.
// Frag (ntile n, kt): lane l, byte e <- W[n*16+(l&15)][kt*32+(l>>4)*8+e]
// ---------------------------------------------------------------------------
__global__ __launch_bounds__(256) void prep_kernel(
    const float* __restrict__ Whh_f, const float* __restrict__ Whh_b,
    const float* __restrict__ Wih_f, const float* __restrict__ Wih_b,
    const float* __restrict__ Wout,
    const float* __restrict__ bih_f, const float* __restrict__ bhh_f,
    const float* __restrict__ bih_b, const float* __restrict__ bhh_b,
    long* __restrict__ whh, long* __restrict__ wih, long* __restrict__ wout,
    float* __restrict__ bias) {
  int bid = blockIdx.x, tid = threadIdx.x;
  if (bid < 256) {  // Whh: gid in [0, 65536)
    int gid = bid * 256 + tid;
    int l = gid & 63, kt = (gid >> 6) & 7, n = (gid >> 9) & 63, dir = gid >> 15;
    const float* src = dir ? Whh_b : Whh_f;
    int row = n * 16 + (l & 15), k0 = kt * 32 + ((l >> 4) << 3);
    float v[8];
#pragma unroll
    for (int e = 0; e < 8; ++e) v[e] = src[row * 256 + k0 + e];
    unsigned lo = pack_fp8x4(v[0], v[1], v[2], v[3]);
    unsigned hi = pack_fp8x4(v[4], v[5], v[6], v[7]);
    whh[gid] = (long)lo | ((long)hi << 32);
  } else if (bid < 384) {  // Wih: gid in [0, 32768)
    int gid = (bid - 256) * 256 + tid;
    int l = gid & 63, kt = (gid >> 6) & 3, n = (gid >> 8) & 63, dir = gid >> 14;
    const float* src = dir ? Wih_b : Wih_f;
    int row = n * 16 + (l & 15), k0 = kt * 32 + ((l >> 4) << 3);
    float v[8];
#pragma unroll
    for (int e = 0; e < 8; ++e) {
      int k = k0 + e;
      v[e] = (k < 100) ? src[row * 100 + k] : 0.f;
    }
    unsigned lo = pack_fp8x4(v[0], v[1], v[2], v[3]);
    unsigned hi = pack_fp8x4(v[4], v[5], v[6], v[7]);
    wih[gid] = (long)lo | ((long)hi << 32);
  } else if (bid < 392) {  // Wout: gid in [0, 2048)
    int gid = (bid - 384) * 256 + tid;
    if (gid < 2048) {
      int l = gid & 63, kt = (gid >> 6) & 7, n = (gid >> 9) & 1, dir = gid >> 10;
      int colt = n * 16 + (l & 15), k0 = kt * 32 + ((l >> 4) << 3);
      float v[8];
#pragma unroll
      for (int e = 0; e < 8; ++e)
        v[e] = (colt < 20) ? Wout[colt * 512 + dir * 256 + k0 + e] : 0.f;
      unsigned lo = pack_fp8x4(v[0], v[1], v[2], v[3]);
      unsigned hi = pack_fp8x4(v[4], v[5], v[6], v[7]);
      wout[gid] = (long)lo | ((long)hi << 32);
    }
  } else {  // bias: idx in [0, 2048)
    int idx = (bid - 392) * 256 + tid;
    if (idx < 2048) {
      int dir = idx >> 10, c = idx & 1023;
      bias[idx] = dir ? (bih_b[c] + bhh_b[c]) : (bih_f[c] + bhh_f[c]);
    }
  }
}

// ---------------------------------------------------------------------------
// K1: BiLSTM recurrence, one WG per (dir, batch-tile). grid=16, block=1024.
// Wave w (0..15) owns 4 ntiles = gate cols [w*64, (w+1)*64).
// 96 VGPR of weights/wave; LDS pad forces 1 block/CU -> 4 waves/SIMD ->
// structural 128-VGPR cap that the demand fits under.
// ---------------------------------------------------------------------------
__global__ __launch_bounds__(1024) void lstm_kernel(
    const int* __restrict__ sent, const float* __restrict__ emb,
    const long* __restrict__ whh, const long* __restrict__ wih,
    const long* __restrict__ wout, const float* __restrict__ bias,
    float* __restrict__ em_out)  // [2][128][512][20]
{
  __shared__ unsigned char h_lds[16][272];      // fp8 h(t-1), 256 data + pad
  __shared__ unsigned char x_lds[2][16][136];   // fp8 x, double-buffered
  __shared__ unsigned short g_T[1024][18];      // bf16 gates [col][row]
  __shared__ long wout_lds[2][8][64];           // fp8 Wout frags [nt][kt][lane]
  __shared__ float bias_lds[1024];
  __shared__ long pad_lds[3072];                // occupancy pin: total 82432B

  const int tid = threadIdx.x;
  const int lid = tid & 63, w = tid >> 6;       // w in 0..15
  const int gid = blockIdx.x, dir = gid >> 3, bt = gid & 7, r0 = bt * 16;

  // keep pad_lds alive (volatile store cannot be DCE'd) -> LDS 82432B
  // -> exactly 1 block/CU (r11-proven mechanism).
  if (tid == 0) *(volatile long*)&pad_lds[0] = 0;

  const int arow = lid & 15;       // A/C tile row-lane
  const int aq = lid >> 4;         // quarter
  const int rb = aq * 4;           // C-frag row base

  // ---- persistent fp8 weights in registers: 4 ntiles -> 96 VGPRs ----
  long wh[4][8], wx[4][4];
  {
    const long* whh_d = whh + dir * 32768;
    const long* wih_d = wih + dir * 16384;
#pragma unroll
    for (int n = 0; n < 4; ++n) {
      int nt = w * 4 + n;
#pragma unroll
      for (int kt = 0; kt < 8; ++kt) wh[n][kt] = whh_d[(nt * 8 + kt) * 64 + lid];
#pragma unroll
      for (int kt = 0; kt < 4; ++kt) wx[n][kt] = wih_d[(nt * 4 + kt) * 64 + lid];
    }
  }
  // remat deterrent: weights become opaque asm outputs
#pragma unroll
  for (int n = 0; n < 4; ++n) {
#pragma unroll
    for (int kt = 0; kt < 8; ++kt) asm volatile("" : "+v"(wh[n][kt]));
#pragma unroll
    for (int kt = 0; kt < 4; ++kt) asm volatile("" : "+v"(wx[n][kt]));
  }

  // Wout + bias -> LDS (1024 longs / 1024 floats, one element per thread)
  {
    const long* wo_d = wout + dir * 1024;
    ((long*)wout_lds)[tid] = wo_d[tid];
    bias_lds[tid] = bias[dir * 1024 + tid];
  }
  // zero h, x (incl. padding)
  for (int i = tid; i < 16 * 272; i += 1024) ((unsigned char*)h_lds)[i] = 0;
  for (int i = tid; i < 2 * 16 * 136; i += 1024) ((unsigned char*)x_lds)[i] = 0;

  // h/c ownership: thread <-> (row ur, hidden cols uc4*4 .. +4)
  const int ur = tid & 15, uc4 = tid >> 4;  // uc4 in 0..63
  float creg[4];
#pragma unroll
  for (int j = 0; j < 4; ++j) creg[j] = 0.f;

  // x gather mapping: 400 chunks = (row 0..15) x (25 float4)
  const int rowA = tid / 25, cgA = tid - rowA * 25;
  const bool hasX = (tid < 400);

  // prologue: stage x(0)
  if (hasX) {
    int t0 = dir ? 511 : 0;
    int sid = sent[(r0 + rowA) * 512 + t0];
    float4 v = *(const float4*)&emb[sid * 100 + cgA * 4];
    *(unsigned*)&x_lds[0][rowA][cgA * 4] = pack_fp8x4(v.x, v.y, v.z, v.w);
  }
  __syncthreads();

  for (int t = 0; t < 512; ++t) {
    // issue x(t+1) gather early (latency hides under the GEMM)
    float4 xN;
    const bool haveN = hasX && (t < 511);
    if (haveN) {
      int te = dir ? (511 - (t + 1)) : (t + 1);
      int sid = sent[(r0 + rowA) * 512 + te];
      xN = *(const float4*)&emb[sid * 100 + cgA * 4];
    }

    const unsigned char(*xb)[136] =
        (const unsigned char(*)[136])x_lds[t & 1];

    // ---- gate GEMM: 4 passes, one ntile each (12 fp8 MFMA / pass) ----
#pragma unroll
    for (int n = 0; n < 4; ++n) {
      const int nt = w * 4 + n;
      float bb = bias_lds[nt * 16 + arow];
      f32x4 acc = {bb, bb, bb, bb};
#pragma unroll
      for (int kt = 0; kt < 8; ++kt) {
        long a8 = *(const long*)&h_lds[arow][kt * 32 + aq * 8];
        acc = MFMAF8(a8, wh[n][kt], acc);
      }
#pragma unroll
      for (int kt = 0; kt < 4; ++kt) {
        long a8 = *(const long*)&xb[arow][kt * 32 + aq * 8];
        acc = MFMAF8(a8, wx[n][kt], acc);
      }
      const int colL = nt * 16 + arow;
      *(unsigned*)&g_T[colL][rb] =
          (unsigned)f2bf(acc[0]) | ((unsigned)f2bf(acc[1]) << 16);
      *(unsigned*)&g_T[colL][rb + 2] =
          (unsigned)f2bf(acc[2]) | ((unsigned)f2bf(acc[3]) << 16);
    }

    // ---- emissions for h(t-1): waves 0-1, h_lds still holds h(t-1) ----
    if (w < 2 && t > 0) {
      f32x4 e = {0.f, 0.f, 0.f, 0.f};
#pragma unroll
      for (int kt = 0; kt < 8; ++kt) {
        long a8 = *(const long*)&h_lds[arow][kt * 32 + aq * 8];
        e = MFMAF8(a8, wout_lds[w][kt][lid], e);
      }
      int col = w * 16 + arow;
      if (col < 20) {
        int tp = dir ? (512 - t) : (t - 1);
        int base = ((dir * 128 + r0 + rb) * 512 + tp) * 20 + col;
#pragma unroll
        for (int r = 0; r < 4; ++r) em_out[base + r * 10240] = e[r];
      }
    }
    __syncthreads();  // B2: gates ready; all h_lds/x reads done

    // ---- h/c update: 4 hidden cols per thread ----
    {
      float hv[4];
#pragma unroll
      for (int j = 0; j < 4; ++j) {
        int c = uc4 * 4 + j;
        float xi = bf2f(g_T[c][ur]);
        float xf = bf2f(g_T[256 + c][ur]);
        float xg = bf2f(g_T[512 + c][ur]);
        float xo = bf2f(g_T[768 + c][ur]);
        float cc = sigm(xf) * creg[j] + sigm(xi) * tanh_(xg);
        creg[j] = cc;
        hv[j] = sigm(xo) * tanh_(cc);
      }
      *(unsigned*)&h_lds[ur][uc4 * 4] = pack_fp8x4(hv[0], hv[1], hv[2], hv[3]);
    }
    // ---- x(t+1) -> LDS (other buffer) ----
    if (haveN) {
      *(unsigned*)&x_lds[(t + 1) & 1][rowA][cgA * 4] =
          pack_fp8x4(xN.x, xN.y, xN.z, xN.w);
    }
    __syncthreads();  // B3: h(t) + x(t+1) staged
  }

  // final emissions for h(511)
  if (w < 2) {
    f32x4 e = {0.f, 0.f, 0.f, 0.f};
#pragma unroll
    for (int kt = 0; kt < 8; ++kt) {
      long a8 = *(const long*)&h_lds[arow][kt * 32 + aq * 8];
      e = MFMAF8(a8, wout_lds[w][kt][lid], e);
    }
    int col = w * 16 + arow;
    if (col < 20) {
      int tp = dir ? 0 : 511;
      int base = ((dir * 128 + r0 + rb) * 512 + tp) * 20 + col;
#pragma unroll
      for (int r = 0; r < 4; ++r) em_out[base + r * 10240] = e[r];
    }
  }
}

// ---------------------------------------------------------------------------
// K2: CRF gold score + forward algorithm. 128 blocks x 64 threads.
// ---------------------------------------------------------------------------
__global__ __launch_bounds__(64) void crf_kernel(
    const float* __restrict__ emf, const float* __restrict__ embk,
    const int* __restrict__ tags, const int* __restrict__ maski,
    const float* __restrict__ bout, const float* __restrict__ trans,
    const float* __restrict__ start_t, const float* __restrict__ end_t,
    float* __restrict__ partial) {
  __shared__ float tr[400];
  const int b = blockIdx.x, tid = threadIdx.x;
  for (int i = tid; i < 400; i += 64) tr[i] = trans[i];
  __syncthreads();

  const int tp = tid;
  const bool act = tp < 20;
  float eT[20];
  if (act) {
#pragma unroll
    for (int t2 = 0; t2 < 20; ++t2) eT[t2] = __expf(tr[t2 * 20 + tp]);
  }
  const float* ef = emf + (size_t)b * 10240;
  const float* eb = embk + (size_t)b * 10240;
  const float bo = act ? bout[tp] : 0.f;

  float a = act ? (start_t[tp] + ef[tp] + eb[tp] + bo) : -1e30f;

  float efn = 0.f, ebn = 0.f;
  if (act) { efn = ef[20 + tp]; ebn = eb[20 + tp]; }

  for (int l = 1; l < 512; ++l) {
    float e_cur = efn + ebn + bo;
    if (act && l + 1 < 512) { efn = ef[(l + 1) * 20 + tp]; ebn = eb[(l + 1) * 20 + tp]; }
    float m = a;
#pragma unroll
    for (int o = 16; o > 0; o >>= 1) m = fmaxf(m, __shfl_xor(m, o, 32));
    float p = __expf(a - m);
    float s = 0.f;
#pragma unroll
    for (int t2 = 0; t2 < 20; ++t2) s += __shfl(p, t2, 32) * eT[t2];
    float anew = m + __logf(s) + e_cur;
    int mk = maski[b * 512 + l];
    if (act && mk) a = anew;
  }
  float v = act ? (a + end_t[tp]) : -1e30f;
  float m2 = v;
#pragma unroll
  for (int o = 16; o > 0; o >>= 1) m2 = fmaxf(m2, __shfl_xor(m2, o, 32));
  float s2 = __expf(v - m2);
#pragma unroll
  for (int o = 16; o > 0; o >>= 1) s2 += __shfl_xor(s2, o, 32);
  float logZ = m2 + __logf(s2);

  const int* tg = tags + b * 512;
  float sc = 0.f;
  int cnt = 0;
  for (int l = tid; l < 512; l += 64) {
    int mk = maski[b * 512 + l];
    cnt += mk ? 1 : 0;
    if (l >= 1 && mk) {
      int cur = tg[l], prev = tg[l - 1];
      sc += tr[prev * 20 + cur] + ef[l * 20 + cur] + eb[l * 20 + cur] + bout[cur];
    }
  }
#pragma unroll
  for (int o = 32; o > 0; o >>= 1) {
    sc += __shfl_xor(sc, o, 64);
    cnt += __shfl_xor(cnt, o, 64);
  }
  if (tid == 0) {
    int t0 = tg[0];
    sc += start_t[t0] + ef[t0] + eb[t0] + bout[t0];
    sc += end_t[tg[cnt - 1]];
    partial[b] = sc - logZ;
  }
}

// ---------------------------------------------------------------------------
// K3: final reduction -> |sum|, f32 output.
// ---------------------------------------------------------------------------
__global__ __launch_bounds__(64) void final_kernel(const float* __restrict__ partial,
                                                   float* __restrict__ out) {
  int tid = threadIdx.x;
  float s = partial[tid] + partial[tid + 64];
#pragma unroll
  for (int o = 32; o > 0; o >>= 1) s += __shfl_xor(s, o, 64);
  if (tid == 0) out[0] = fabsf(s);
}

// ---------------------------------------------------------------------------
extern "C" void kernel_launch(void* const* d_in, const int* in_sizes, int n_in,
                              void* d_out, int out_size, void* d_ws, size_t ws_size,
                              hipStream_t stream) {
  const int* sent = (const int*)d_in[0];
  const int* tags = (const int*)d_in[1];
  const int* maski = (const int*)d_in[2];
  const float* emb = (const float*)d_in[3];
  const float* Wih_f = (const float*)d_in[4];
  const float* Whh_f = (const float*)d_in[5];
  const float* bih_f = (const float*)d_in[6];
  const float* bhh_f = (const float*)d_in[7];
  const float* Wih_b = (const float*)d_in[8];
  const float* Whh_b = (const float*)d_in[9];
  const float* bih_b = (const float*)d_in[10];
  const float* bhh_b = (const float*)d_in[11];
  const float* Wout = (const float*)d_in[12];
  const float* bout = (const float*)d_in[13];
  const float* trans = (const float*)d_in[14];
  const float* start_t = (const float*)d_in[15];
  const float* end_t = (const float*)d_in[16];

  char* ws = (char*)d_ws;
  float* em_base = (float*)ws;
  float* em_f = em_base;
  float* em_b = em_base + 128 * 512 * 20;
  long* whh_f8 = (long*)(ws + 10485760);
  long* wih_f8 = (long*)(ws + 11010048);
  long* wout_f8 = (long*)(ws + 11272192);
  float* bias_d = (float*)(ws + 11288576);
  float* partial = (float*)(ws + 11296768);

  prep_kernel<<<400, 256, 0, stream>>>(Whh_f, Whh_b, Wih_f, Wih_b, Wout,
                                       bih_f, bhh_f, bih_b, bhh_b,
                                       whh_f8, wih_f8, wout_f8, bias_d);
  lstm_kernel<<<16, 1024, 0, stream>>>(sent, emb, whh_f8, wih_f8, wout_f8,
                                       bias_d, em_base);
  crf_kernel<<<128, 64, 0, stream>>>(em_f, em_b, tags, maski, bout, trans,
                                     start_t, end_t, partial);
  final_kernel<<<1, 64, 0, stream>>>(partial, (float*)d_out);
}

// Round 13
// 1731.853 us; speedup vs baseline: 1.5393x; 1.5393x over previous
//
#include <hip/hip_runtime.h>

// ---------------------------------------------------------------------------
// BiLSTM-CRF forward loss on MI355X (gfx950).
//
// Round-13: obey the empirical allocator law (r6-r12): 512-thr kernels get
// 128 VGPR, 1024-thr get 64 -- no hint changes it. So make residency fit:
//   - 2 WGs per (dir,bt) group, split by HIDDEN-COLUMN HALVES: WG half owns
//     hidden cols [half*128,+128) and the i/f/g/o gate slices for exactly
//     those cols (update fully local). Wave (of 8) owns 4 ntiles ->
//     wh[4][8]+wx[4][4] = 96 VGPR weights + ~30 working < 128.
//   - halves exchange their 2KB fp8 h-slice per step via the r5-PROVEN
//     fence-free atomic protocol (relaxed agent atomics; __syncthreads
//     drains vmcnt before flag; double-buffered parity; poll flag>=t).
//     Pairs (bid, bid+16) share an XCD under round-robin dispatch.
//   - LDS padded to exactly 57856B (r6-proven 128-VGPR config).
// Contract notes (rounds 0-3): output f32; mask int32.
// Workspace layout (bytes):
//   [0)         em: [2][128][512][20] f32            (10485760)
//   [10485760)  whh_f8: [2][64nt][8kt][64lane] i64   (524288)
//   [11010048)  wih_f8: [2][64nt][4kt][64lane] i64   (262144)
//   [11272192)  wout_f8: [2][2nt][8kt][64lane] i64   (16384)
//   [11288576)  bias: [2][1024] f32                  (8192)
//   [11296768)  partial: [128] f32                   (512)
//   [11297280)  flags: [16 pair][2 half] int         (128)
//   [11300864)  h_glob: [2 par][16 pair][16][256] fp8 (131072)
// ---------------------------------------------------------------------------

typedef float f32x4 __attribute__((ext_vector_type(4)));

#define MFMAF8(a, b, c) \
  __builtin_amdgcn_mfma_f32_16x16x32_fp8_fp8((a), (b), (c), 0, 0, 0)
#define ATOMIC_LD(p) __hip_atomic_load((p), __ATOMIC_RELAXED, __HIP_MEMORY_SCOPE_AGENT)
#define ATOMIC_ST(p, v) \
  __hip_atomic_store((p), (v), __ATOMIC_RELAXED, __HIP_MEMORY_SCOPE_AGENT)

__device__ __forceinline__ unsigned short f2bf(float x) {
  unsigned u = __float_as_uint(x);
  u += 0x7FFFu + ((u >> 16) & 1u);  // RNE
  return (unsigned short)(u >> 16);
}
__device__ __forceinline__ float bf2f(unsigned short h) {
  return __uint_as_float(((unsigned)h) << 16);
}
__device__ __forceinline__ float sigm(float x) {
  return __builtin_amdgcn_rcpf(1.f + __expf(-x));
}
__device__ __forceinline__ float tanh_(float x) {
  float e = __expf(2.f * x);
  return (e - 1.f) * __builtin_amdgcn_rcpf(e + 1.f);
}
__device__ __forceinline__ unsigned pack_fp8x4(float a, float b, float c, float d) {
  int p = __builtin_amdgcn_cvt_pk_fp8_f32(a, b, 0, false);
  p = __builtin_amdgcn_cvt_pk_fp8_f32(c, d, p, true);
  return (unsigned)p;
}

// ---------------------------------------------------------------------------
// K0: weight prep: f32 -> fp8 e4m3 MFMA B-fragments; + flag zeroing (bid 400).
// Frag (ntile n, kt): lane l, byte e <- W[n*16+(l&15)][kt*32+(l>>4)*8+e]
// ---------------------------------------------------------------------------
__global__ __launch_bounds__(256) void prep_kernel(
    const float* __restrict__ Whh_f, const float* __restrict__ Whh_b,
    const float* __restrict__ Wih_f, const float* __restrict__ Wih_b,
    const float* __restrict__ Wout,
    const float* __restrict__ bih_f, const float* __restrict__ bhh_f,
    const float* __restrict__ bih_b, const float* __restrict__ bhh_b,
    long* __restrict__ whh, long* __restrict__ wih, long* __restrict__ wout,
    float* __restrict__ bias, int* __restrict__ flags) {
  int bid = blockIdx.x, tid = threadIdx.x;
  if (bid < 256) {  // Whh: gid in [0, 65536)
    int gid = bid * 256 + tid;
    int l = gid & 63, kt = (gid >> 6) & 7, n = (gid >> 9) & 63, dir = gid >> 15;
    const float* src = dir ? Whh_b : Whh_f;
    int row = n * 16 + (l & 15), k0 = kt * 32 + ((l >> 4) << 3);
    float v[8];
#pragma unroll
    for (int e = 0; e < 8; ++e) v[e] = src[row * 256 + k0 + e];
    unsigned lo = pack_fp8x4(v[0], v[1], v[2], v[3]);
    unsigned hi = pack_fp8x4(v[4], v[5], v[6], v[7]);
    whh[gid] = (long)lo | ((long)hi << 32);
  } else if (bid < 384) {  // Wih: gid in [0, 32768)
    int gid = (bid - 256) * 256 + tid;
    int l = gid & 63, kt = (gid >> 6) & 3, n = (gid >> 8) & 63, dir = gid >> 14;
    const float* src = dir ? Wih_b : Wih_f;
    int row = n * 16 + (l & 15), k0 = kt * 32 + ((l >> 4) << 3);
    float v[8];
#pragma unroll
    for (int e = 0; e < 8; ++e) {
      int k = k0 + e;
      v[e] = (k < 100) ? src[row * 100 + k] : 0.f;
    }
    unsigned lo = pack_fp8x4(v[0], v[1], v[2], v[3]);
    unsigned hi = pack_fp8x4(v[4], v[5], v[6], v[7]);
    wih[gid] = (long)lo | ((long)hi << 32);
  } else if (bid < 392) {  // Wout: gid in [0, 2048)
    int gid = (bid - 384) * 256 + tid;
    if (gid < 2048) {
      int l = gid & 63, kt = (gid >> 6) & 7, n = (gid >> 9) & 1, dir = gid >> 10;
      int colt = n * 16 + (l & 15), k0 = kt * 32 + ((l >> 4) << 3);
      float v[8];
#pragma unroll
      for (int e = 0; e < 8; ++e)
        v[e] = (colt < 20) ? Wout[colt * 512 + dir * 256 + k0 + e] : 0.f;
      unsigned lo = pack_fp8x4(v[0], v[1], v[2], v[3]);
      unsigned hi = pack_fp8x4(v[4], v[5], v[6], v[7]);
      wout[gid] = (long)lo | ((long)hi << 32);
    }
  } else if (bid < 400) {  // bias: idx in [0, 2048)
    int idx = (bid - 392) * 256 + tid;
    if (idx < 2048) {
      int dir = idx >> 10, c = idx & 1023;
      bias[idx] = dir ? (bih_b[c] + bhh_b[c]) : (bih_f[c] + bhh_f[c]);
    }
  } else {  // flags
    if (tid < 32) flags[tid] = 0;
  }
}

// ---------------------------------------------------------------------------
// K1: BiLSTM recurrence. grid = 32 (pair p = bid&15 = dir*8+bt, half = bid>>4),
// block = 512 (8 waves). Wave w: gate g=w>>1, sub s=w&1; owns 4 ntiles
// nt(n) = g*16 + half*8 + s*4 + n  (96 VGPR of fp8 weight frags).
// Per step: 48 MFMA gate GEMM -> local h/c update of 128 own hidden cols ->
// 2KB fp8 h-slice exchange with the peer half (fence-free atomics).
// ---------------------------------------------------------------------------
__global__ __launch_bounds__(512) void lstm_kernel(
    const int* __restrict__ sent, const float* __restrict__ emb,
    const long* __restrict__ whh, const long* __restrict__ wih,
    const long* __restrict__ wout, const float* __restrict__ bias,
    float* __restrict__ em_out, unsigned char* __restrict__ h_glob,
    int* __restrict__ flags)
{
  __shared__ unsigned char h_lds[16][272];     // fp8 h(t-1), full 256 cols
  __shared__ unsigned char x_lds[2][16][136];  // fp8 x, double-buffered
  __shared__ unsigned short g_T[512][18];      // bf16 local gates [lcol][row]
  __shared__ long wout_lds[2][8][64];          // fp8 Wout frags
  __shared__ float bias_lds[1024];
  __shared__ long pad_lds[2304];               // total LDS = 57856 B (r6 cfg)

  const int tid = threadIdx.x;
  const int lid = tid & 63, w = tid >> 6;
  const int p = blockIdx.x & 15, half = blockIdx.x >> 4;
  const int dir = p >> 3, bt = p & 7, r0 = bt * 16;
  const int ph = 1 - half;

  if (tid == 0) *(volatile long*)&pad_lds[0] = 0;  // keep pad (no DCE)

  const int arow = lid & 15;
  const int aq = lid >> 4;
  const int rb = aq * 4;
  const int g = w >> 1, s = w & 1;

  // ---- persistent fp8 weights: 4 ntiles -> 96 VGPRs ----
  long wh[4][8], wx[4][4];
  {
    const long* whh_d = whh + dir * 32768;
    const long* wih_d = wih + dir * 16384;
#pragma unroll
    for (int n = 0; n < 4; ++n) {
      int nt = g * 16 + half * 8 + s * 4 + n;
#pragma unroll
      for (int kt = 0; kt < 8; ++kt) wh[n][kt] = whh_d[(nt * 8 + kt) * 64 + lid];
#pragma unroll
      for (int kt = 0; kt < 4; ++kt) wx[n][kt] = wih_d[(nt * 4 + kt) * 64 + lid];
    }
  }
#pragma unroll
  for (int n = 0; n < 4; ++n) {
#pragma unroll
    for (int kt = 0; kt < 8; ++kt) asm volatile("" : "+v"(wh[n][kt]));
#pragma unroll
    for (int kt = 0; kt < 4; ++kt) asm volatile("" : "+v"(wx[n][kt]));
  }

  // Wout + bias -> LDS
  {
    const long* wo_d = wout + dir * 1024;
    ((long*)wout_lds)[tid] = wo_d[tid];
    ((long*)wout_lds)[tid + 512] = wo_d[tid + 512];
    bias_lds[tid] = bias[dir * 1024 + tid];
    bias_lds[tid + 512] = bias[dir * 1024 + tid + 512];
  }
  for (int i = tid; i < 16 * 272; i += 512) ((unsigned char*)h_lds)[i] = 0;
  for (int i = tid; i < 2 * 16 * 136; i += 512) ((unsigned char*)x_lds)[i] = 0;

  // h/c ownership: thread <-> (row ur, own LOCAL cols jb..jb+4)
  const int ur = tid & 15, jb = (tid >> 4) * 4;  // jb in 0..124
  float creg[4];
#pragma unroll
  for (int j = 0; j < 4; ++j) creg[j] = 0.f;

  unsigned* hb0 = (unsigned*)(h_glob + p * 4096);           // parity 0
  unsigned* hb1 = (unsigned*)(h_glob + 65536 + p * 4096);   // parity 1
  int* fl = flags + p * 2;

  // x gather mapping: 400 chunks = (row 0..15) x (25 float4)
  const int rowA = tid / 25, cgA = tid - rowA * 25;
  const bool hasX = (tid < 400);

  if (hasX) {  // stage x(0)
    int t0 = dir ? 511 : 0;
    int sid = sent[(r0 + rowA) * 512 + t0];
    float4 v = *(const float4*)&emb[sid * 100 + cgA * 4];
    *(unsigned*)&x_lds[0][rowA][cgA * 4] = pack_fp8x4(v.x, v.y, v.z, v.w);
  }
  __syncthreads();

  for (int t = 0; t < 512; ++t) {
    // issue x(t+1) gather early
    float4 xN;
    const bool haveN = hasX && (t < 511);
    if (haveN) {
      int te = dir ? (511 - (t + 1)) : (t + 1);
      int sid = sent[(r0 + rowA) * 512 + te];
      xN = *(const float4*)&emb[sid * 100 + cgA * 4];
    }

    if (t > 0) {
      if (tid == 0) {
        while (ATOMIC_LD(&fl[ph]) < t) __builtin_amdgcn_s_sleep(2);
      }
      __syncthreads();  // A: peer h(t-1) visible; prev-iter h_lds reads done
      unsigned* srcw = (t & 1) ? hb0 : hb1;  // parity (t-1)&1
      {
        int row = tid >> 5, wc = tid & 31;
        unsigned wv = ATOMIC_LD(&srcw[row * 64 + ph * 32 + wc]);
        *(unsigned*)&h_lds[row][ph * 128 + wc * 4] = wv;
      }
    }
    __syncthreads();  // B1: full h(t-1) + x(t) staged

    const unsigned char(*xb)[136] = (const unsigned char(*)[136])x_lds[t & 1];

    // ---- gate GEMM: 48 fp8 MFMA (kt outer, 4 ntiles inner) ----
    {
      f32x4 acc[4];
#pragma unroll
      for (int n = 0; n < 4; ++n) {
        float bb = bias_lds[(g * 16 + half * 8 + s * 4 + n) * 16 + arow];
        f32x4 a = {bb, bb, bb, bb};
        acc[n] = a;
      }
#pragma unroll
      for (int kt = 0; kt < 8; ++kt) {
        long a8 = *(const long*)&h_lds[arow][kt * 32 + aq * 8];
#pragma unroll
        for (int n = 0; n < 4; ++n) acc[n] = MFMAF8(a8, wh[n][kt], acc[n]);
      }
#pragma unroll
      for (int kt = 0; kt < 4; ++kt) {
        long a8 = *(const long*)&xb[arow][kt * 32 + aq * 8];
#pragma unroll
        for (int n = 0; n < 4; ++n) acc[n] = MFMAF8(a8, wx[n][kt], acc[n]);
      }
#pragma unroll
      for (int n = 0; n < 4; ++n) {
        int lcol = (w * 4 + n) * 16 + arow;  // local gate col
        *(unsigned*)&g_T[lcol][rb] =
            (unsigned)f2bf(acc[n][0]) | ((unsigned)f2bf(acc[n][1]) << 16);
        *(unsigned*)&g_T[lcol][rb + 2] =
            (unsigned)f2bf(acc[n][2]) | ((unsigned)f2bf(acc[n][3]) << 16);
      }
    }

    // ---- emissions for h(t-1): half-0 WG, waves 0-1 ----
    if (half == 0 && w < 2 && t > 0) {
      f32x4 e = {0.f, 0.f, 0.f, 0.f};
#pragma unroll
      for (int kt = 0; kt < 8; ++kt) {
        long a8 = *(const long*)&h_lds[arow][kt * 32 + aq * 8];
        e = MFMAF8(a8, wout_lds[w][kt][lid], e);
      }
      int col = w * 16 + arow;
      if (col < 20) {
        int tp = dir ? (512 - t) : (t - 1);
        int base = ((dir * 128 + r0 + rb) * 512 + tp) * 20 + col;
#pragma unroll
        for (int r = 0; r < 4; ++r) em_out[base + r * 10240] = e[r];
      }
    }
    __syncthreads();  // B2: gates ready; all h_lds/x reads done

    // ---- h/c update: own 128 local cols (4 per thread) ----
    {
      float hv[4];
#pragma unroll
      for (int j = 0; j < 4; ++j) {
        int c = jb + j;
        float xi = bf2f(g_T[c][ur]);
        float xf = bf2f(g_T[128 + c][ur]);
        float xg = bf2f(g_T[256 + c][ur]);
        float xo = bf2f(g_T[384 + c][ur]);
        float cc = sigm(xf) * creg[j] + sigm(xi) * tanh_(xg);
        creg[j] = cc;
        hv[j] = sigm(xo) * tanh_(cc);
      }
      unsigned pk = pack_fp8x4(hv[0], hv[1], hv[2], hv[3]);
      *(unsigned*)&h_lds[ur][half * 128 + jb] = pk;     // own half -> LDS
      unsigned* dstw = (t & 1) ? hb1 : hb0;             // parity t&1
      ATOMIC_ST(&dstw[ur * 64 + half * 32 + (jb >> 2)], pk);  // publish
    }
    // ---- x(t+1) -> LDS (other buffer) ----
    if (haveN) {
      *(unsigned*)&x_lds[(t + 1) & 1][rowA][cgA * 4] =
          pack_fp8x4(xN.x, xN.y, xN.z, xN.w);
    }
    __syncthreads();  // B3: drains vmcnt (publish acked); h_lds own half set
    if (tid == 0) ATOMIC_ST(&fl[half], t + 1);
  }

  // final emissions for h(511): half-0 assembles peer half from parity 1
  if (half == 0) {
    if (tid == 0) {
      while (ATOMIC_LD(&fl[1]) < 512) __builtin_amdgcn_s_sleep(2);
    }
    __syncthreads();
    {
      int row = tid >> 5, wc = tid & 31;
      unsigned wv = ATOMIC_LD(&hb1[row * 64 + 32 + wc]);
      *(unsigned*)&h_lds[row][128 + wc * 4] = wv;
    }
    __syncthreads();
    if (w < 2) {
      f32x4 e = {0.f, 0.f, 0.f, 0.f};
#pragma unroll
      for (int kt = 0; kt < 8; ++kt) {
        long a8 = *(const long*)&h_lds[arow][kt * 32 + aq * 8];
        e = MFMAF8(a8, wout_lds[w][kt][lid], e);
      }
      int col = w * 16 + arow;
      if (col < 20) {
        int tp = dir ? 0 : 511;
        int base = ((dir * 128 + r0 + rb) * 512 + tp) * 20 + col;
#pragma unroll
        for (int r = 0; r < 4; ++r) em_out[base + r * 10240] = e[r];
      }
    }
  }
}

// ---------------------------------------------------------------------------
// K2: CRF gold score + forward algorithm. 128 blocks x 64 threads.
// ---------------------------------------------------------------------------
__global__ __launch_bounds__(64) void crf_kernel(
    const float* __restrict__ emf, const float* __restrict__ embk,
    const int* __restrict__ tags, const int* __restrict__ maski,
    const float* __restrict__ bout, const float* __restrict__ trans,
    const float* __restrict__ start_t, const float* __restrict__ end_t,
    float* __restrict__ partial) {
  __shared__ float tr[400];
  const int b = blockIdx.x, tid = threadIdx.x;
  for (int i = tid; i < 400; i += 64) tr[i] = trans[i];
  __syncthreads();

  const int tp = tid;
  const bool act = tp < 20;
  float eT[20];
  if (act) {
#pragma unroll
    for (int t2 = 0; t2 < 20; ++t2) eT[t2] = __expf(tr[t2 * 20 + tp]);
  }
  const float* ef = emf + (size_t)b * 10240;
  const float* eb = embk + (size_t)b * 10240;
  const float bo = act ? bout[tp] : 0.f;

  float a = act ? (start_t[tp] + ef[tp] + eb[tp] + bo) : -1e30f;

  float efn = 0.f, ebn = 0.f;
  if (act) { efn = ef[20 + tp]; ebn = eb[20 + tp]; }

  for (int l = 1; l < 512; ++l) {
    float e_cur = efn + ebn + bo;
    if (act && l + 1 < 512) { efn = ef[(l + 1) * 20 + tp]; ebn = eb[(l + 1) * 20 + tp]; }
    float m = a;
#pragma unroll
    for (int o = 16; o > 0; o >>= 1) m = fmaxf(m, __shfl_xor(m, o, 32));
    float pv = __expf(a - m);
    float sgm = 0.f;
#pragma unroll
    for (int t2 = 0; t2 < 20; ++t2) sgm += __shfl(pv, t2, 32) * eT[t2];
    float anew = m + __logf(sgm) + e_cur;
    int mk = maski[b * 512 + l];
    if (act && mk) a = anew;
  }
  float v = act ? (a + end_t[tp]) : -1e30f;
  float m2 = v;
#pragma unroll
  for (int o = 16; o > 0; o >>= 1) m2 = fmaxf(m2, __shfl_xor(m2, o, 32));
  float s2 = __expf(v - m2);
#pragma unroll
  for (int o = 16; o > 0; o >>= 1) s2 += __shfl_xor(s2, o, 32);
  float logZ = m2 + __logf(s2);

  const int* tg = tags + b * 512;
  float sc = 0.f;
  int cnt = 0;
  for (int l = tid; l < 512; l += 64) {
    int mk = maski[b * 512 + l];
    cnt += mk ? 1 : 0;
    if (l >= 1 && mk) {
      int cur = tg[l], prev = tg[l - 1];
      sc += tr[prev * 20 + cur] + ef[l * 20 + cur] + eb[l * 20 + cur] + bout[cur];
    }
  }
#pragma unroll
  for (int o = 32; o > 0; o >>= 1) {
    sc += __shfl_xor(sc, o, 64);
    cnt += __shfl_xor(cnt, o, 64);
  }
  if (tid == 0) {
    int t0 = tg[0];
    sc += start_t[t0] + ef[t0] + eb[t0] + bout[t0];
    sc += end_t[tg[cnt - 1]];
    partial[b] = sc - logZ;
  }
}

// ---------------------------------------------------------------------------
// K3: final reduction -> |sum|, f32 output.
// ---------------------------------------------------------------------------
__global__ __launch_bounds__(64) void final_kernel(const float* __restrict__ partial,
                                                   float* __restrict__ out) {
  int tid = threadIdx.x;
  float s = partial[tid] + partial[tid + 64];
#pragma unroll
  for (int o = 32; o > 0; o >>= 1) s += __shfl_xor(s, o, 64);
  if (tid == 0) out[0] = fabsf(s);
}

// ---------------------------------------------------------------------------
extern "C" void kernel_launch(void* const* d_in, const int* in_sizes, int n_in,
                              void* d_out, int out_size, void* d_ws, size_t ws_size,
                              hipStream_t stream) {
  const int* sent = (const int*)d_in[0];
  const int* tags = (const int*)d_in[1];
  const int* maski = (const int*)d_in[2];
  const float* emb = (const float*)d_in[3];
  const float* Wih_f = (const float*)d_in[4];
  const float* Whh_f = (const float*)d_in[5];
  const float* bih_f = (const float*)d_in[6];
  const float* bhh_f = (const float*)d_in[7];
  const float* Wih_b = (const float*)d_in[8];
  const float* Whh_b = (const float*)d_in[9];
  const float* bih_b = (const float*)d_in[10];
  const float* bhh_b = (const float*)d_in[11];
  const float* Wout = (const float*)d_in[12];
  const float* bout = (const float*)d_in[13];
  const float* trans = (const float*)d_in[14];
  const float* start_t = (const float*)d_in[15];
  const float* end_t = (const float*)d_in[16];

  char* ws = (char*)d_ws;
  float* em_base = (float*)ws;
  float* em_f = em_base;
  float* em_b = em_base + 128 * 512 * 20;
  long* whh_f8 = (long*)(ws + 10485760);
  long* wih_f8 = (long*)(ws + 11010048);
  long* wout_f8 = (long*)(ws + 11272192);
  float* bias_d = (float*)(ws + 11288576);
  float* partial = (float*)(ws + 11296768);
  int* flags = (int*)(ws + 11297280);
  unsigned char* h_glob = (unsigned char*)(ws + 11300864);

  prep_kernel<<<401, 256, 0, stream>>>(Whh_f, Whh_b, Wih_f, Wih_b, Wout,
                                       bih_f, bhh_f, bih_b, bhh_b,
                                       whh_f8, wih_f8, wout_f8, bias_d, flags);
  lstm_kernel<<<32, 512, 0, stream>>>(sent, emb, whh_f8, wih_f8, wout_f8,
                                      bias_d, em_base, h_glob, flags);
  crf_kernel<<<128, 64, 0, stream>>>(em_f, em_b, tags, maski, bout, trans,
                                     start_t, end_t, partial);
  final_kernel<<<1, 64, 0, stream>>>(partial, (float*)d_out);
}

// Round 14
// 1332.445 us; speedup vs baseline: 2.0007x; 1.2998x over previous
//
#include <hip/hip_runtime.h>

// ---------------------------------------------------------------------------
// BiLSTM-CRF forward loss on MI355X (gfx950).
//
// Round-14: 4-way hidden-column split + overlap (evolves r13's proven 2-way).
//   r13 decode: per-step 2.97us = stream(192KB/CU, 1.28) + exchange(0.9) +
//   compute(0.8). Both terms attacked:
//   - 4 WGs per (dir,bt) group (grid=64). Wave owns 2 ntiles -> 48 VGPR of
//     fp8 weights (r13 allocated 84 -> this SHOULD finally stay resident;
//     even if not, stream halves to 96KB/step).
//   - Peer h reads issued into REGISTERS right after the flag poll; own-K
//     GEMM (own h-ktiles are local) runs while loads are in flight; then
//     stage->LDS->peer-K GEMM. Weight regs reordered wh[n][j] with
//     kt=(2q+j)&7 so all register indices stay compile-time (rule #20).
//   - Emissions on q1/q2 wave0 (1 ntile each), off q0's critical path.
//   - r5/r13-proven fence-free atomic exchange; LDS padded to the proven
//     57856B config; volatile-kept pad.
// Contract notes (rounds 0-3): output f32; mask int32.
// Workspace layout (bytes):
//   [0)         em: [2][128][512][20] f32            (10485760)
//   [10485760)  whh_f8: [2][64nt][8kt][64lane] i64   (524288)
//   [11010048)  wih_f8: [2][64nt][4kt][64lane] i64   (262144)
//   [11272192)  wout_f8: [2][2nt][8kt][64lane] i64   (16384)
//   [11288576)  bias: [2][1024] f32                  (8192)
//   [11296768)  partial: [128] f32                   (512)
//   [11297280)  flags: [16 group][4 quarter] int     (256)
//   [11300864)  h_glob: [2 par][16 group][16][256] fp8 (131072)
// ---------------------------------------------------------------------------

typedef float f32x4 __attribute__((ext_vector_type(4)));

#define MFMAF8(a, b, c) \
  __builtin_amdgcn_mfma_f32_16x16x32_fp8_fp8((a), (b), (c), 0, 0, 0)
#define ATOMIC_LD(p) __hip_atomic_load((p), __ATOMIC_RELAXED, __HIP_MEMORY_SCOPE_AGENT)
#define ATOMIC_ST(p, v) \
  __hip_atomic_store((p), (v), __ATOMIC_RELAXED, __HIP_MEMORY_SCOPE_AGENT)

__device__ __forceinline__ unsigned short f2bf(float x) {
  unsigned u = __float_as_uint(x);
  u += 0x7FFFu + ((u >> 16) & 1u);  // RNE
  return (unsigned short)(u >> 16);
}
__device__ __forceinline__ float bf2f(unsigned short h) {
  return __uint_as_float(((unsigned)h) << 16);
}
__device__ __forceinline__ float sigm(float x) {
  return __builtin_amdgcn_rcpf(1.f + __expf(-x));
}
__device__ __forceinline__ float tanh_(float x) {
  float e = __expf(2.f * x);
  return (e - 1.f) * __builtin_amdgcn_rcpf(e + 1.f);
}
__device__ __forceinline__ unsigned pack_fp8x4(float a, float b, float c, float d) {
  int p = __builtin_amdgcn_cvt_pk_fp8_f32(a, b, 0, false);
  p = __builtin_amdgcn_cvt_pk_fp8_f32(c, d, p, true);
  return (unsigned)p;
}

// ---------------------------------------------------------------------------
// K0: weight prep: f32 -> fp8 e4m3 MFMA B-fragments; + flag zeroing (bid 400).
// Frag (ntile n, kt): lane l, byte e <- W[n*16+(l&15)][kt*32+(l>>4)*8+e]
// ---------------------------------------------------------------------------
__global__ __launch_bounds__(256) void prep_kernel(
    const float* __restrict__ Whh_f, const float* __restrict__ Whh_b,
    const float* __restrict__ Wih_f, const float* __restrict__ Wih_b,
    const float* __restrict__ Wout,
    const float* __restrict__ bih_f, const float* __restrict__ bhh_f,
    const float* __restrict__ bih_b, const float* __restrict__ bhh_b,
    long* __restrict__ whh, long* __restrict__ wih, long* __restrict__ wout,
    float* __restrict__ bias, int* __restrict__ flags) {
  int bid = blockIdx.x, tid = threadIdx.x;
  if (bid < 256) {  // Whh: gid in [0, 65536)
    int gid = bid * 256 + tid;
    int l = gid & 63, kt = (gid >> 6) & 7, n = (gid >> 9) & 63, dir = gid >> 15;
    const float* src = dir ? Whh_b : Whh_f;
    int row = n * 16 + (l & 15), k0 = kt * 32 + ((l >> 4) << 3);
    float v[8];
#pragma unroll
    for (int e = 0; e < 8; ++e) v[e] = src[row * 256 + k0 + e];
    unsigned lo = pack_fp8x4(v[0], v[1], v[2], v[3]);
    unsigned hi = pack_fp8x4(v[4], v[5], v[6], v[7]);
    whh[gid] = (long)lo | ((long)hi << 32);
  } else if (bid < 384) {  // Wih: gid in [0, 32768)
    int gid = (bid - 256) * 256 + tid;
    int l = gid & 63, kt = (gid >> 6) & 3, n = (gid >> 8) & 63, dir = gid >> 14;
    const float* src = dir ? Wih_b : Wih_f;
    int row = n * 16 + (l & 15), k0 = kt * 32 + ((l >> 4) << 3);
    float v[8];
#pragma unroll
    for (int e = 0; e < 8; ++e) {
      int k = k0 + e;
      v[e] = (k < 100) ? src[row * 100 + k] : 0.f;
    }
    unsigned lo = pack_fp8x4(v[0], v[1], v[2], v[3]);
    unsigned hi = pack_fp8x4(v[4], v[5], v[6], v[7]);
    wih[gid] = (long)lo | ((long)hi << 32);
  } else if (bid < 392) {  // Wout: gid in [0, 2048)
    int gid = (bid - 384) * 256 + tid;
    if (gid < 2048) {
      int l = gid & 63, kt = (gid >> 6) & 7, n = (gid >> 9) & 1, dir = gid >> 10;
      int colt = n * 16 + (l & 15), k0 = kt * 32 + ((l >> 4) << 3);
      float v[8];
#pragma unroll
      for (int e = 0; e < 8; ++e)
        v[e] = (colt < 20) ? Wout[colt * 512 + dir * 256 + k0 + e] : 0.f;
      unsigned lo = pack_fp8x4(v[0], v[1], v[2], v[3]);
      unsigned hi = pack_fp8x4(v[4], v[5], v[6], v[7]);
      wout[gid] = (long)lo | ((long)hi << 32);
    }
  } else if (bid < 400) {  // bias: idx in [0, 2048)
    int idx = (bid - 392) * 256 + tid;
    if (idx < 2048) {
      int dir = idx >> 10, c = idx & 1023;
      bias[idx] = dir ? (bih_b[c] + bhh_b[c]) : (bih_f[c] + bhh_f[c]);
    }
  } else {  // flags: 16 groups x 4 quarters
    if (tid < 64) flags[tid] = 0;
  }
}

// ---------------------------------------------------------------------------
// K1: BiLSTM recurrence. grid = 64 (group p = bid&15 = dir*8+bt, quarter
// q = bid>>4), block = 512 (8 waves). Wave w: gate g=w>>1, sub s=w&1; owns
// 2 ntiles nt(n) = g*16 + q*4 + s*2 + n (48 VGPR of fp8 weight frags,
// kt-order rotated so own h-ktiles sit at j=0,1: wh[n][j], kt=(2q+j)&7).
// Per step: poll -> issue 3 peer-slice reads (regs) -> ownK GEMM (overlap)
// -> stage peer h -> peerK GEMM -> update own 64 hidden cols -> publish 1KB.
// ---------------------------------------------------------------------------
__global__ __launch_bounds__(512) void lstm_kernel(
    const int* __restrict__ sent, const float* __restrict__ emb,
    const long* __restrict__ whh, const long* __restrict__ wih,
    const long* __restrict__ wout, const float* __restrict__ bias,
    float* __restrict__ em_out, unsigned char* __restrict__ h_glob,
    int* __restrict__ flags)
{
  __shared__ unsigned char h_lds[16][272];     // fp8 h(t-1), full 256 cols
  __shared__ unsigned char x_lds[2][16][136];  // fp8 x, double-buffered
  __shared__ unsigned short g_T[256][18];      // bf16 local gates [lcol][row]
  __shared__ long wout_lds[2][8][64];          // fp8 Wout frags
  __shared__ float bias_lds[1024];
  __shared__ long pad_lds[3456];               // total LDS = 57856 B

  const int tid = threadIdx.x;
  const int lid = tid & 63, w = tid >> 6;
  const int p = blockIdx.x & 15, q = blockIdx.x >> 4;
  const int dir = p >> 3, bt = p & 7, r0 = bt * 16;

  if (tid == 0) *(volatile long*)&pad_lds[0] = 0;  // keep pad (no DCE)

  const int arow = lid & 15;
  const int aq = lid >> 4;
  const int rb = aq * 4;
  const int g = w >> 1, s = w & 1;

  // ---- persistent fp8 weights: 2 ntiles -> 48 VGPRs; kt rotated by 2q ----
  long wh[2][8], wx[2][4];
  {
    const long* whh_d = whh + dir * 32768;
    const long* wih_d = wih + dir * 16384;
#pragma unroll
    for (int n = 0; n < 2; ++n) {
      int nt = g * 16 + q * 4 + s * 2 + n;
#pragma unroll
      for (int j = 0; j < 8; ++j) {
        int kt = (2 * q + j) & 7;
        wh[n][j] = whh_d[(nt * 8 + kt) * 64 + lid];
      }
#pragma unroll
      for (int kt = 0; kt < 4; ++kt) wx[n][kt] = wih_d[(nt * 4 + kt) * 64 + lid];
    }
  }
#pragma unroll
  for (int n = 0; n < 2; ++n) {
#pragma unroll
    for (int j = 0; j < 8; ++j) asm volatile("" : "+v"(wh[n][j]));
#pragma unroll
    for (int kt = 0; kt < 4; ++kt) asm volatile("" : "+v"(wx[n][kt]));
  }

  // Wout + bias -> LDS
  {
    const long* wo_d = wout + dir * 1024;
    ((long*)wout_lds)[tid] = wo_d[tid];
    ((long*)wout_lds)[tid + 512] = wo_d[tid + 512];
    bias_lds[tid] = bias[dir * 1024 + tid];
    bias_lds[tid + 512] = bias[dir * 1024 + tid + 512];
  }
  for (int i = tid; i < 16 * 272; i += 512) ((unsigned char*)h_lds)[i] = 0;
  for (int i = tid; i < 2 * 16 * 136; i += 512) ((unsigned char*)x_lds)[i] = 0;

  // h/c ownership: thread <-> (row ur, own LOCAL cols jb..jb+2)
  const int ur = tid & 15, jb = (tid >> 4) * 2;  // jb in 0..62
  float creg[2];
  creg[0] = 0.f;
  creg[1] = 0.f;

  unsigned* hb0 = (unsigned*)(h_glob + p * 4096);          // parity 0
  unsigned* hb1 = (unsigned*)(h_glob + 65536 + p * 4096);  // parity 1
  int* fl = flags + p * 4;

  // peer quarters
  const int pqa = (q + 1) & 3, pqb = (q + 2) & 3, pqc = (q + 3) & 3;

  // x gather mapping: 400 chunks = (row 0..15) x (25 float4)
  const int rxA = tid / 25, cxA = tid - rxA * 25;
  const bool hasX = (tid < 400);

  if (hasX) {  // stage x(0)
    int t0 = dir ? 511 : 0;
    int sid = sent[(r0 + rxA) * 512 + t0];
    float4 v = *(const float4*)&emb[sid * 100 + cxA * 4];
    *(unsigned*)&x_lds[0][rxA][cxA * 4] = pack_fp8x4(v.x, v.y, v.z, v.w);
  }
  __syncthreads();

  // prefetch-role mapping (fixed per thread)
  const int prow = (tid & 255) >> 4, pwq = tid & 15;
  const bool roleA = (tid < 256);  // loads pqa + pqc; else pqb

  for (int t = 0; t < 512; ++t) {
    // issue x(t+1) gather early
    float4 xN;
    const bool haveN = hasX && (t < 511);
    if (haveN) {
      int te = dir ? (511 - (t + 1)) : (t + 1);
      int sid = sent[(r0 + rxA) * 512 + te];
      xN = *(const float4*)&emb[sid * 100 + cxA * 4];
    }

    unsigned wa = 0, wb2 = 0, wc = 0;
    if (t > 0) {
      if (tid < 3) {
        int pq = (q + 1 + tid) & 3;
        while (ATOMIC_LD(&fl[pq]) < t) __builtin_amdgcn_s_sleep(2);
      }
      __syncthreads();  // S0: peers' h(t-1) published & drained
      unsigned* srcw = (t & 1) ? hb0 : hb1;  // parity (t-1)&1
      if (roleA) {
        wa = ATOMIC_LD(&srcw[prow * 64 + pqa * 16 + pwq]);
        wc = ATOMIC_LD(&srcw[prow * 64 + pqc * 16 + pwq]);
      } else {
        wb2 = ATOMIC_LD(&srcw[prow * 64 + pqb * 16 + pwq]);
      }
    }

    const unsigned char(*xb)[136] = (const unsigned char(*)[136])x_lds[t & 1];

    // ---- ownK GEMM: j=0,1 (own h-ktiles, local) + x; overlaps peer reads --
    f32x4 acc[2];
#pragma unroll
    for (int n = 0; n < 2; ++n) {
      float bb = bias_lds[(g * 16 + q * 4 + s * 2 + n) * 16 + arow];
      f32x4 a = {bb, bb, bb, bb};
      acc[n] = a;
    }
#pragma unroll
    for (int j = 0; j < 2; ++j) {
      int kt = 2 * q + j;  // no wrap for j<2
      long a8 = *(const long*)&h_lds[arow][kt * 32 + aq * 8];
      acc[0] = MFMAF8(a8, wh[0][j], acc[0]);
      acc[1] = MFMAF8(a8, wh[1][j], acc[1]);
    }
#pragma unroll
    for (int kt = 0; kt < 4; ++kt) {
      long a8 = *(const long*)&xb[arow][kt * 32 + aq * 8];
      acc[0] = MFMAF8(a8, wx[0][kt], acc[0]);
      acc[1] = MFMAF8(a8, wx[1][kt], acc[1]);
    }

    // ---- stage peer h(t-1) -> LDS (waits on the in-flight reads) ----
    if (t > 0) {
      if (roleA) {
        *(unsigned*)&h_lds[prow][pqa * 64 + pwq * 4] = wa;
        *(unsigned*)&h_lds[prow][pqc * 64 + pwq * 4] = wc;
      } else {
        *(unsigned*)&h_lds[prow][pqb * 64 + pwq * 4] = wb2;
      }
    }
    __syncthreads();  // S1: full h(t-1) staged

    // ---- peerK GEMM: j=2..7 ----
#pragma unroll
    for (int j = 2; j < 8; ++j) {
      int kt = (2 * q + j) & 7;
      long a8 = *(const long*)&h_lds[arow][kt * 32 + aq * 8];
      acc[0] = MFMAF8(a8, wh[0][j], acc[0]);
      acc[1] = MFMAF8(a8, wh[1][j], acc[1]);
    }
#pragma unroll
    for (int n = 0; n < 2; ++n) {
      int lcol = (w * 2 + n) * 16 + arow;
      *(unsigned*)&g_T[lcol][rb] =
          (unsigned)f2bf(acc[n][0]) | ((unsigned)f2bf(acc[n][1]) << 16);
      *(unsigned*)&g_T[lcol][rb + 2] =
          (unsigned)f2bf(acc[n][2]) | ((unsigned)f2bf(acc[n][3]) << 16);
    }

    // ---- emissions for h(t-1): q1 wave0 -> ntile0, q2 wave0 -> ntile1 ----
    if (t > 0 && w == 0 && (q == 1 || q == 2)) {
      int nt = q - 1;
      f32x4 e = {0.f, 0.f, 0.f, 0.f};
#pragma unroll
      for (int kt = 0; kt < 8; ++kt) {
        long a8 = *(const long*)&h_lds[arow][kt * 32 + aq * 8];
        e = MFMAF8(a8, wout_lds[nt][kt][lid], e);
      }
      int col = nt * 16 + arow;
      if (col < 20) {
        int tp = dir ? (512 - t) : (t - 1);
        int base = ((dir * 128 + r0 + rb) * 512 + tp) * 20 + col;
#pragma unroll
        for (int r = 0; r < 4; ++r) em_out[base + r * 10240] = e[r];
      }
    }
    __syncthreads();  // S2: gates ready; all h_lds reads done

    // ---- h/c update: own 64 local cols (2 per thread) ----
    {
      float hv[2];
#pragma unroll
      for (int j = 0; j < 2; ++j) {
        int c = jb + j;
        float xi = bf2f(g_T[c][ur]);
        float xf = bf2f(g_T[64 + c][ur]);
        float xg = bf2f(g_T[128 + c][ur]);
        float xo = bf2f(g_T[192 + c][ur]);
        float cc = sigm(xf) * creg[j] + sigm(xi) * tanh_(xg);
        creg[j] = cc;
        hv[j] = sigm(xo) * tanh_(cc);
      }
      unsigned pk =
          (unsigned)__builtin_amdgcn_cvt_pk_fp8_f32(hv[0], hv[1], 0, false);
      *(unsigned short*)&h_lds[ur][q * 64 + jb] = (unsigned short)pk;
    }
    __syncthreads();  // S3: own h(t) in LDS; g_T reads done

    // ---- publish own 1KB slice + x(t+1) stage ----
    {
      unsigned* dstw = (t & 1) ? hb1 : hb0;  // parity t&1
      if (tid < 256) {
        int row = tid >> 4, wq = tid & 15;
        unsigned word = *(const unsigned*)&h_lds[row][q * 64 + wq * 4];
        ATOMIC_ST(&dstw[row * 64 + q * 16 + wq], word);
      }
    }
    if (haveN) {
      *(unsigned*)&x_lds[(t + 1) & 1][rxA][cxA * 4] =
          pack_fp8x4(xN.x, xN.y, xN.z, xN.w);
    }
    __syncthreads();  // S4: drains vmcnt (publish acked); x staged
    if (tid == 0) ATOMIC_ST(&fl[q], t + 1);
  }

  // ---- epilogue: emissions for h(511) (q1/q2 wave0) ----
  if (tid < 3) {
    int pq = (q + 1 + tid) & 3;
    while (ATOMIC_LD(&fl[pq]) < 512) __builtin_amdgcn_s_sleep(2);
  }
  __syncthreads();
  {  // stage peer h(511) from parity 1
    if (roleA) {
      unsigned wa2 = ATOMIC_LD(&hb1[prow * 64 + pqa * 16 + pwq]);
      unsigned wc2 = ATOMIC_LD(&hb1[prow * 64 + pqc * 16 + pwq]);
      *(unsigned*)&h_lds[prow][pqa * 64 + pwq * 4] = wa2;
      *(unsigned*)&h_lds[prow][pqc * 64 + pwq * 4] = wc2;
    } else {
      unsigned wb3 = ATOMIC_LD(&hb1[prow * 64 + pqb * 16 + pwq]);
      *(unsigned*)&h_lds[prow][pqb * 64 + pwq * 4] = wb3;
    }
  }
  __syncthreads();
  if (w == 0 && (q == 1 || q == 2)) {
    int nt = q - 1;
    f32x4 e = {0.f, 0.f, 0.f, 0.f};
#pragma unroll
    for (int kt = 0; kt < 8; ++kt) {
      long a8 = *(const long*)&h_lds[arow][kt * 32 + aq * 8];
      e = MFMAF8(a8, wout_lds[nt][kt][lid], e);
    }
    int col = nt * 16 + arow;
    if (col < 20) {
      int tp = dir ? 0 : 511;
      int base = ((dir * 128 + r0 + rb) * 512 + tp) * 20 + col;
#pragma unroll
      for (int r = 0; r < 4; ++r) em_out[base + r * 10240] = e[r];
    }
  }
}

// ---------------------------------------------------------------------------
// K2: CRF gold score + forward algorithm. 128 blocks x 64 threads.
// ---------------------------------------------------------------------------
__global__ __launch_bounds__(64) void crf_kernel(
    const float* __restrict__ emf, const float* __restrict__ embk,
    const int* __restrict__ tags, const int* __restrict__ maski,
    const float* __restrict__ bout, const float* __restrict__ trans,
    const float* __restrict__ start_t, const float* __restrict__ end_t,
    float* __restrict__ partial) {
  __shared__ float tr[400];
  const int b = blockIdx.x, tid = threadIdx.x;
  for (int i = tid; i < 400; i += 64) tr[i] = trans[i];
  __syncthreads();

  const int tp = tid;
  const bool act = tp < 20;
  float eT[20];
  if (act) {
#pragma unroll
    for (int t2 = 0; t2 < 20; ++t2) eT[t2] = __expf(tr[t2 * 20 + tp]);
  }
  const float* ef = emf + (size_t)b * 10240;
  const float* eb = embk + (size_t)b * 10240;
  const float bo = act ? bout[tp] : 0.f;

  float a = act ? (start_t[tp] + ef[tp] + eb[tp] + bo) : -1e30f;

  float efn = 0.f, ebn = 0.f;
  if (act) { efn = ef[20 + tp]; ebn = eb[20 + tp]; }

  for (int l = 1; l < 512; ++l) {
    float e_cur = efn + ebn + bo;
    if (act && l + 1 < 512) { efn = ef[(l + 1) * 20 + tp]; ebn = eb[(l + 1) * 20 + tp]; }
    float m = a;
#pragma unroll
    for (int o = 16; o > 0; o >>= 1) m = fmaxf(m, __shfl_xor(m, o, 32));
    float pv = __expf(a - m);
    float sgm = 0.f;
#pragma unroll
    for (int t2 = 0; t2 < 20; ++t2) sgm += __shfl(pv, t2, 32) * eT[t2];
    float anew = m + __logf(sgm) + e_cur;
    int mk = maski[b * 512 + l];
    if (act && mk) a = anew;
  }
  float v = act ? (a + end_t[tp]) : -1e30f;
  float m2 = v;
#pragma unroll
  for (int o = 16; o > 0; o >>= 1) m2 = fmaxf(m2, __shfl_xor(m2, o, 32));
  float s2 = __expf(v - m2);
#pragma unroll
  for (int o = 16; o > 0; o >>= 1) s2 += __shfl_xor(s2, o, 32);
  float logZ = m2 + __logf(s2);

  const int* tg = tags + b * 512;
  float sc = 0.f;
  int cnt = 0;
  for (int l = tid; l < 512; l += 64) {
    int mk = maski[b * 512 + l];
    cnt += mk ? 1 : 0;
    if (l >= 1 && mk) {
      int cur = tg[l], prev = tg[l - 1];
      sc += tr[prev * 20 + cur] + ef[l * 20 + cur] + eb[l * 20 + cur] + bout[cur];
    }
  }
#pragma unroll
  for (int o = 32; o > 0; o >>= 1) {
    sc += __shfl_xor(sc, o, 64);
    cnt += __shfl_xor(cnt, o, 64);
  }
  if (tid == 0) {
    int t0 = tg[0];
    sc += start_t[t0] + ef[t0] + eb[t0] + bout[t0];
    sc += end_t[tg[cnt - 1]];
    partial[b] = sc - logZ;
  }
}

// ---------------------------------------------------------------------------
// K3: final reduction -> |sum|, f32 output.
// ---------------------------------------------------------------------------
__global__ __launch_bounds__(64) void final_kernel(const float* __restrict__ partial,
                                                   float* __restrict__ out) {
  int tid = threadIdx.x;
  float s = partial[tid] + partial[tid + 64];
#pragma unroll
  for (int o = 32; o > 0; o >>= 1) s += __shfl_xor(s, o, 64);
  if (tid == 0) out[0] = fabsf(s);
}

// ---------------------------------------------------------------------------
extern "C" void kernel_launch(void* const* d_in, const int* in_sizes, int n_in,
                              void* d_out, int out_size, void* d_ws, size_t ws_size,
                              hipStream_t stream) {
  const int* sent = (const int*)d_in[0];
  const int* tags = (const int*)d_in[1];
  const int* maski = (const int*)d_in[2];
  const float* emb = (const float*)d_in[3];
  const float* Wih_f = (const float*)d_in[4];
  const float* Whh_f = (const float*)d_in[5];
  const float* bih_f = (const float*)d_in[6];
  const float* bhh_f = (const float*)d_in[7];
  const float* Wih_b = (const float*)d_in[8];
  const float* Whh_b = (const float*)d_in[9];
  const float* bih_b = (const float*)d_in[10];
  const float* bhh_b = (const float*)d_in[11];
  const float* Wout = (const float*)d_in[12];
  const float* bout = (const float*)d_in[13];
  const float* trans = (const float*)d_in[14];
  const float* start_t = (const float*)d_in[15];
  const float* end_t = (const float*)d_in[16];

  char* ws = (char*)d_ws;
  float* em_base = (float*)ws;
  float* em_f = em_base;
  float* em_b = em_base + 128 * 512 * 20;
  long* whh_f8 = (long*)(ws + 10485760);
  long* wih_f8 = (long*)(ws + 11010048);
  long* wout_f8 = (long*)(ws + 11272192);
  float* bias_d = (float*)(ws + 11288576);
  float* partial = (float*)(ws + 11296768);
  int* flags = (int*)(ws + 11297280);
  unsigned char* h_glob = (unsigned char*)(ws + 11300864);

  prep_kernel<<<401, 256, 0, stream>>>(Whh_f, Whh_b, Wih_f, Wih_b, Wout,
                                       bih_f, bhh_f, bih_b, bhh_b,
                                       whh_f8, wih_f8, wout_f8, bias_d, flags);
  lstm_kernel<<<64, 512, 0, stream>>>(sent, emb, whh_f8, wih_f8, wout_f8,
                                      bias_d, em_base, h_glob, flags);
  crf_kernel<<<128, 64, 0, stream>>>(em_f, em_b, tags, maski, bout, trans,
                                     start_t, end_t, partial);
  final_kernel<<<1, 64, 0, stream>>>(partial, (float*)d_out);
}